// Round 10
// baseline (177.521 us; speedup 1.0000x reference)
//
#include <hip/hip_runtime.h>
#include <math.h>

#define BB 32
#define LL 256
#define DD 16
#define HH 64
#define KK 5
#define TT 252          // LL - KK + 1
#define PP 126          // TT/2
#define SS 8064         // HH*PP
#define NCHUNK 42
#define CHUNK 192       // SS / NCHUNK
#define KSTEP 16
#define NKT (CHUNK / KSTEP)   // 12
#define BCOLS 256       // cols per block
#define NCB 32          // 32 * 256 = 8192 >= 8064

// ---------------- kernel 12: conv + relu + recon + pool (fused per (b,d)) --
__global__ __launch_bounds__(256) void k12_conv_recon(
    const float* __restrict__ x, const float* __restrict__ cw,
    const float* __restrict__ cb, const float* __restrict__ dw,
    const float* __restrict__ db, float* __restrict__ flat,
    float* __restrict__ mainT, float* __restrict__ recon) {
  __shared__ float ylds[HH * TT];   // 64*252 = 16128 f = 64512 B
  __shared__ float xs[LL];
  __shared__ float cws[HH * KK];
  __shared__ float dws[HH * KK];
  __shared__ float cbs[HH];

  int bd = blockIdx.x;              // b*DD + d
  int b = bd / DD, d = bd % DD;
  int tid = threadIdx.x;

  xs[tid] = x[((size_t)b * LL + tid) * DD + d];
  for (int i = tid; i < HH * KK; i += 256) {
    cws[i] = cw[(size_t)d * HH * KK + i];
    dws[i] = dw[(size_t)d * HH * KK + i];
  }
  if (tid < HH) cbs[tid] = cb[d * HH + tid];
  __syncthreads();

  {
    int h = tid >> 2, a = tid & 3;
    int t0 = a * 63;
    float w0 = cws[h * KK + 0], w1 = cws[h * KK + 1], w2 = cws[h * KK + 2],
          w3 = cws[h * KK + 3], w4 = cws[h * KK + 4];
    float bias = cbs[h];
    float x0 = xs[t0], x1 = xs[t0 + 1], x2 = xs[t0 + 2], x3 = xs[t0 + 3],
          x4 = xs[t0 + 4];
    float* yrow = ylds + h * TT + t0;
    #pragma unroll 7
    for (int t = 0; t < 63; ++t) {
      float yv = fmaf(w4, x4, fmaf(w3, x3, fmaf(w2, x2, fmaf(w1, x1, fmaf(w0, x0, bias)))));
      yrow[t] = fmaxf(yv, 0.f);
      x0 = x1; x1 = x2; x2 = x3; x3 = x4;
      if (t < 62) x4 = xs[t0 + t + 5];
    }
  }
  __syncthreads();

  for (int i = tid; i < HH * PP; i += 256) {
    int h = i / PP, p = i - h * PP;
    float pooled = 0.5f * (ylds[h * TT + 2 * p] + ylds[h * TT + 2 * p + 1]);
    flat[(size_t)bd * SS + i] = pooled;
    if (d == 0) mainT[(size_t)i * BB + b] = pooled;   // [s][b]
  }

  {
    int l = tid;
    float acc = db[d];
    for (int h = 0; h < HH; ++h) {
      const float* yl = ylds + h * TT;
      #pragma unroll
      for (int j = 0; j < KK; ++j) {
        int t = l - j;
        if (t >= 0 && t < TT) acc = fmaf(yl[t], dws[h * KK + j], acc);
      }
    }
    recon[(size_t)bd * LL + l] = acc;
  }
}

// ---------------- kernel 3: partial = main @ W_attn -------------------------
// Register-blocked GEMM: thread tile 8 batches x 4 cols (8 NAMED float4 accs).
// W tile (16x256) double-buffered in LDS (reg-staged, 1 barrier/tile);
// m fragment = 2 wave-uniform float4 global loads per k-step (L2 broadcast).
// Per k-step/thread: 1 ds_read_b128 + 2 uniform loads feed 32 FMAs.
#define FMA4V(A, WF, S)                                       \
  A.x = fmaf(WF.x, S, A.x); A.y = fmaf(WF.y, S, A.y);         \
  A.z = fmaf(WF.z, S, A.z); A.w = fmaf(WF.w, S, A.w);

__global__ __launch_bounds__(256) void k3_matmul(
    const float* __restrict__ W, const float* __restrict__ mainT,
    float* __restrict__ partial) {
  __shared__ float wlds[2][KSTEP * BCOLS];   // 2 x 16 x 256 x 4B = 32 KB
  int chunk = blockIdx.y;
  int s0 = chunk * CHUNK;
  int colbase = blockIdx.x * BCOLS;
  int tid = threadIdx.x;
  int br = tid >> 6;       // 0..3 (8 batches each)
  int cg = tid & 63;       // 0..63 (4 cols each)
  int gc = colbase + cg * 4;
  int gcl = gc > SS - 4 ? SS - 4 : gc;   // clamped staging col (last block)

  float4 z = make_float4(0.f, 0.f, 0.f, 0.f);
  float4 A0 = z, A1 = z, A2 = z, A3 = z, A4 = z, A5 = z, A6 = z, A7 = z;
  float4 r0, r1, r2, r3;   // staging regs: rows {br, br+4, br+8, br+12}

#define LOADREGS(KT) {                                                    \
    const float* src = W + (size_t)(s0 + (KT) * KSTEP + br) * SS + gcl;   \
    r0 = *(const float4*)(src);                                           \
    r1 = *(const float4*)(src + 4 * (size_t)SS);                          \
    r2 = *(const float4*)(src + 8 * (size_t)SS);                          \
    r3 = *(const float4*)(src + 12 * (size_t)SS); }

#define WRITEB(BUF) {                                                     \
    float* dst = &wlds[BUF][br * BCOLS + cg * 4];                         \
    *(float4*)(dst)             = r0;                                     \
    *(float4*)(dst + 4 * BCOLS) = r1;                                     \
    *(float4*)(dst + 8 * BCOLS) = r2;                                     \
    *(float4*)(dst + 12 * BCOLS) = r3; }

#define COMPUTE(BUF, KT) {                                                \
    const float* mrow = mainT + (size_t)(s0 + (KT) * KSTEP) * BB + br * 8;\
    _Pragma("unroll")                                                     \
    for (int kk = 0; kk < KSTEP; ++kk) {                                  \
      float4 wf = *(const float4*)&wlds[BUF][kk * BCOLS + cg * 4];        \
      float4 m0 = *(const float4*)(mrow + kk * BB);                       \
      float4 m1 = *(const float4*)(mrow + kk * BB + 4);                   \
      FMA4V(A0, wf, m0.x) FMA4V(A1, wf, m0.y)                             \
      FMA4V(A2, wf, m0.z) FMA4V(A3, wf, m0.w)                             \
      FMA4V(A4, wf, m1.x) FMA4V(A5, wf, m1.y)                             \
      FMA4V(A6, wf, m1.z) FMA4V(A7, wf, m1.w)                             \
    } }

  // prologue: tile0 -> LDS buf0; tile1 -> regs
  LOADREGS(0)
  WRITEB(0)
  LOADREGS(1)
  __syncthreads();

  for (int kt = 0; kt < NKT; ++kt) {
    if (kt + 1 < NKT) { WRITEB((kt + 1) & 1) }      // regs(kt+1) -> other buf
    if (kt + 2 < NKT) { LOADREGS(kt + 2) }          // issue next global loads
    COMPUTE(kt & 1, kt)
    __syncthreads();   // readers of cur done + writes to next visible
  }

  if (gc < SS) {
    float* pp = partial + ((size_t)chunk * BB + br * 8) * SS + gc;
    *(float4*)(pp)                 = A0;
    *(float4*)(pp + 1 * (size_t)SS) = A1;
    *(float4*)(pp + 2 * (size_t)SS) = A2;
    *(float4*)(pp + 3 * (size_t)SS) = A3;
    *(float4*)(pp + 4 * (size_t)SS) = A4;
    *(float4*)(pp + 5 * (size_t)SS) = A5;
    *(float4*)(pp + 6 * (size_t)SS) = A6;
    *(float4*)(pp + 7 * (size_t)SS) = A7;
  }
#undef LOADREGS
#undef WRITEB
#undef COMPUTE
}

// ---------------- kernel 3b: reduce partials -> m (float4) ------------------
__global__ __launch_bounds__(64) void k3b_reduce(
    const float4* __restrict__ partial, float4* __restrict__ m) {
  int i = blockIdx.x * 64 + threadIdx.x;       // < BB*SS/4 = 64512
  float4 s = make_float4(0.f, 0.f, 0.f, 0.f);
  #pragma unroll
  for (int c = 0; c < NCHUNK; ++c) {
    float4 v = partial[(size_t)c * (BB * SS / 4) + i];
    s.x += v.x; s.y += v.y; s.z += v.z; s.w += v.w;
  }
  m[i] = s;
}

// ---------------- kernel 4: scores[b,d'] = <m[b,:], aux[b,d',:]> ------------
__global__ __launch_bounds__(256) void k4_scores(
    const float* __restrict__ m, const float* __restrict__ flat,
    float* __restrict__ scores) {
  int bd = blockIdx.x;            // b*15 + dd
  int b = bd / 15, dd = bd % 15;
  const float* mb = m + (size_t)b * SS;
  const float* ab = flat + ((size_t)b * DD + 1 + dd) * SS;
  float p = 0.f;
  for (int s = threadIdx.x; s < SS; s += 256) p = fmaf(mb[s], ab[s], p);
  #pragma unroll
  for (int o = 32; o; o >>= 1) p += __shfl_xor(p, o);
  __shared__ float red[4];
  if ((threadIdx.x & 63) == 0) red[threadIdx.x >> 6] = p;
  __syncthreads();
  if (threadIdx.x == 0) scores[bd] = red[0] + red[1] + red[2] + red[3];
}

// ---------------- kernel 5: softmax over 15 ---------------------------------
__global__ __launch_bounds__(64) void k5_softmax(
    const float* __restrict__ scores, float* __restrict__ attn_out) {
  int b = blockIdx.x;
  int lane = threadIdx.x;
  float v = (lane < 15) ? scores[b * 15 + lane] : -INFINITY;
  float mx = v;
  #pragma unroll
  for (int o = 32; o; o >>= 1) mx = fmaxf(mx, __shfl_xor(mx, o));
  float e = (lane < 15) ? expf(v - mx) : 0.f;
  float sum = e;
  #pragma unroll
  for (int o = 32; o; o >>= 1) sum += __shfl_xor(sum, o);
  if (lane < 15) attn_out[b * 15 + lane] = e / sum;
}

// ---------------- kernel 6: main copy + weighted sum ------------------------
__global__ __launch_bounds__(256) void k6_out(
    const float* __restrict__ flat, const float* __restrict__ attn,
    float* __restrict__ out) {
  int b = blockIdx.y;
  int s = blockIdx.x * 256 + threadIdx.x;
  if (s >= SS) return;
  const float* fb = flat + (size_t)b * DD * SS;
  out[(size_t)b * 2 * SS + s] = fb[s];
  float w = 0.f;
  #pragma unroll
  for (int d = 0; d < 15; ++d)
    w = fmaf(attn[b * 15 + d], fb[(size_t)(1 + d) * SS + s], w);
  out[(size_t)b * 2 * SS + SS + s] = w;
}

// ---------------------------------------------------------------------------
extern "C" void kernel_launch(void* const* d_in, const int* in_sizes, int n_in,
                              void* d_out, int out_size, void* d_ws, size_t ws_size,
                              hipStream_t stream) {
  const float* x        = (const float*)d_in[0];
  const float* conv_w   = (const float*)d_in[1];
  const float* conv_b   = (const float*)d_in[2];
  const float* deconv_w = (const float*)d_in[3];
  const float* deconv_b = (const float*)d_in[4];
  const float* W_attn   = (const float*)d_in[5];
  float* out = (float*)d_out;

  // output layout: [ out (516096) | attn (480) | recon (131072) ]
  const size_t ATTN_OFF  = (size_t)BB * 2 * SS;        // 516096
  const size_t RECON_OFF = ATTN_OFF + (size_t)BB * 15; // 516576

  // workspace layout (floats); all offsets multiple of 4 -> 16B aligned
  float* ws      = (float*)d_ws;
  float* partial = ws;                                    // 42*32*8064 = 10,838,016
  float* flat    = partial + (size_t)NCHUNK * BB * SS;    // 4,128,768
  float* mainT   = flat + (size_t)BB * DD * SS;           // 258,048  [s][b]
  float* m       = mainT + (size_t)BB * SS;               // 258,048  [b][s]
  float* scores  = m + (size_t)BB * SS;                   // 480

  // 1) fused conv+relu+recon+pool
  k12_conv_recon<<<dim3(BB * DD), dim3(256), 0, stream>>>(
      x, conv_w, conv_b, deconv_w, deconv_b, flat, mainT, out + RECON_OFF);

  // 2) big matmul partials
  k3_matmul<<<dim3(NCB, NCHUNK), dim3(256), 0, stream>>>(W_attn, mainT, partial);

  // 3) reduce -> m
  k3b_reduce<<<dim3((BB * SS / 4) / 64), dim3(64), 0, stream>>>(
      (const float4*)partial, (float4*)m);

  // 4) scores
  k4_scores<<<dim3(BB * 15), dim3(256), 0, stream>>>(m, flat, scores);

  // 5) softmax -> attn section of out
  k5_softmax<<<dim3(BB), dim3(64), 0, stream>>>(scores, out + ATTN_OFF);

  // 6) main copy + weighted
  k6_out<<<dim3((SS + 255) / 256, BB), dim3(256), 0, stream>>>(
      flat, out + ATTN_OFF, out);
}